// Round 5
// baseline (262.027 us; speedup 1.0000x reference)
//
#include <hip/hip_runtime.h>

#define B_  4
#define T_  2048
#define C_  1024
#define H_  16
#define D_  64
#define BT_ 8192

typedef __bf16 bf16x8 __attribute__((ext_vector_type(8)));
typedef float  f32x4  __attribute__((ext_vector_type(4)));

#define MFMA(a, b, c) __builtin_amdgcn_mfma_f32_16x16x32_bf16((a), (b), (c), 0, 0, 0)
#define LOG2E 1.4426950408889634f

__device__ __forceinline__ float fexp2(float x) {
#if __has_builtin(__builtin_amdgcn_exp2f)
    return __builtin_amdgcn_exp2f(x);
#else
    return __expf(x * 0.6931471805599453f);
#endif
}

__device__ __forceinline__ unsigned short f2bf(float f) {
    union { float f; unsigned u; } v; v.f = f;
    unsigned r = v.u + 0x7FFFu + ((v.u >> 16) & 1u);   // RTNE
    return (unsigned short)(r >> 16);
}

// async global->LDS, 16B per lane (m97 pattern)
__device__ __forceinline__ void gll16(const unsigned short* g, unsigned short* l) {
    __builtin_amdgcn_global_load_lds((const __attribute__((address_space(1))) void*)g,
                                     (__attribute__((address_space(3))) void*)l, 16, 0, 0);
}

// Stage one 1KB chunk (64 lanes x 16B): GPR 16B-granules per row, XOR-swizzled.
template <int GPR>
__device__ __forceinline__ void stage16(const unsigned short* grow0, size_t stride_us,
                                        unsigned short* lds, int chunk) {
    const int lane = threadIdx.x & 63;
    const int gidx = chunk * 64 + lane;
    const int row  = gidx / GPR, c = gidx % GPR;
    const int csrc = c ^ (row & (GPR - 1));
    gll16(grow0 + (size_t)row * stride_us + csrc * 8, lds + gidx * 8);
}

// ---------------- fused prep: x->bf16 convert + both weight transposes ----------------
// blocks [0,8192): convert; [8192,11264): W_attn^T; [11264,12288): W_proj^T
__global__ __launch_bounds__(256) void prep_kernel(const float* __restrict__ x,
                                                   unsigned short* __restrict__ xb,
                                                   const float* __restrict__ Wa,
                                                   unsigned short* __restrict__ Wab,
                                                   const float* __restrict__ Wp,
                                                   unsigned short* __restrict__ Wpb) {
    __shared__ float tile[32][33];
    const int bid = blockIdx.x;
    if (bid < 8192) {
        int i = bid * 1024 + threadIdx.x * 4;
        float4 v = *(const float4*)&x[i];
        ushort4 o;
        o.x = f2bf(v.x); o.y = f2bf(v.y); o.z = f2bf(v.z); o.w = f2bf(v.w);
        *(ushort4*)&xb[i] = o;
        return;
    }
    const float* in; unsigned short* out; int N, t;
    if (bid < 11264) { t = bid - 8192;  in = Wa; out = Wab; N = 3072; }
    else             { t = bid - 11264; in = Wp; out = Wpb; N = 1024; }
    const int n0 = (t % (N / 32)) * 32, k0 = (t / (N / 32)) * 32;   // K=1024
    const int tr = threadIdx.x >> 3, tc = (threadIdx.x & 7) * 4;
    float4 v = *(const float4*)&in[(size_t)(k0 + tr) * N + n0 + tc];
    tile[tr][tc + 0] = v.x; tile[tr][tc + 1] = v.y;
    tile[tr][tc + 2] = v.z; tile[tr][tc + 3] = v.w;
    __syncthreads();
    ushort4 o;
    o.x = f2bf(tile[tc + 0][tr]);
    o.y = f2bf(tile[tc + 1][tr]);
    o.z = f2bf(tile[tc + 2][tr]);
    o.w = f2bf(tile[tc + 3][tr]);
    *(ushort4*)&out[(size_t)(n0 + tr) * 1024 + k0 + tc] = o;
}

// ---------------- fallback: transpose v-section of qkv -> vT [BH,D,T] ----------------
__global__ __launch_bounds__(256) void transpose_v_kernel(const unsigned short* __restrict__ qkv,
                                                          unsigned short* __restrict__ vT) {
    __shared__ unsigned short tile[64][65];
    const int bh = blockIdx.y;
    const int b = bh >> 4, h = bh & 15;
    const int t0 = blockIdx.x * 64;
    const size_t src = (size_t)b * 2048 * 3072 + 2048 + h * 64;
    const size_t dbase = (size_t)bh * (T_ * D_);
    const int r = threadIdx.x >> 2, c = (threadIdx.x & 3) * 16;
    uint4 a0 = *(const uint4*)&qkv[src + (size_t)(t0 + r) * 3072 + c];
    uint4 a1 = *(const uint4*)&qkv[src + (size_t)(t0 + r) * 3072 + c + 8];
    const unsigned short* ap = (const unsigned short*)&a0;
    #pragma unroll
    for (int i = 0; i < 8; ++i) tile[r][c + i] = ap[i];
    ap = (const unsigned short*)&a1;
    #pragma unroll
    for (int i = 0; i < 8; ++i) tile[r][c + 8 + i] = ap[i];
    __syncthreads();
    unsigned short tmp[16];
    #pragma unroll
    for (int i = 0; i < 16; ++i) tmp[i] = tile[c + i][r];
    *(uint4*)&vT[dbase + (size_t)r * T_ + t0 + c]     = *(uint4*)&tmp[0];
    *(uint4*)&vT[dbase + (size_t)r * T_ + t0 + c + 8] = *(uint4*)&tmp[8];
}

// ---------------- 128x128 bf16 MFMA GEMM (m97 staging) — kept for proj + fallback ----------------
template <int MODE, int VDIRECT>
__global__ __launch_bounds__(256) void gemm_bf16_kernel(
    const unsigned short* __restrict__ A,
    const unsigned short* __restrict__ Bt,
    const float* __restrict__ bias,
    float* __restrict__ outF,
    unsigned short* __restrict__ outB,
    unsigned short* __restrict__ vTout,
    int M, int N, int K)
{
    __shared__ __align__(16) unsigned short smem[(MODE == 0 && VDIRECT) ? 10240 : 8192];
    unsigned short* As = smem;          // [128][32], swizzled granules
    unsigned short* Bs = smem + 4096;
    const int tid = threadIdx.x;
    const int wave = tid >> 6, lane = tid & 63;
    const int wr = wave >> 1, wc = wave & 1;
    const int g = lane >> 4, li = lane & 15;
    const int m0 = blockIdx.y * 128, n0 = blockIdx.x * 128;

    f32x4 acc[4][4] = {};

    for (int k0 = 0; k0 < K; k0 += 32) {
        __syncthreads();
        stage16<4>(A  + (size_t)m0 * K + k0, K, As, wave * 2);
        stage16<4>(A  + (size_t)m0 * K + k0, K, As, wave * 2 + 1);
        stage16<4>(Bt + (size_t)n0 * K + k0, K, Bs, wave * 2);
        stage16<4>(Bt + (size_t)n0 * K + k0, K, Bs, wave * 2 + 1);
        __syncthreads();
        bf16x8 af[4], bfr[4];
        #pragma unroll
        for (int mi = 0; mi < 4; ++mi) {
            const int row = wr * 64 + mi * 16 + li;
            af[mi] = *(const bf16x8*)&As[row * 32 + ((g ^ (row & 3)) * 8)];
        }
        #pragma unroll
        for (int ni = 0; ni < 4; ++ni) {
            const int row = wc * 64 + ni * 16 + li;
            bfr[ni] = *(const bf16x8*)&Bs[row * 32 + ((g ^ (row & 3)) * 8)];
        }
        #pragma unroll
        for (int mi = 0; mi < 4; ++mi)
            #pragma unroll
            for (int ni = 0; ni < 4; ++ni)
                acc[mi][ni] = MFMA(af[mi], bfr[ni], acc[mi][ni]);
    }

    float bb[4];
    #pragma unroll
    for (int ni = 0; ni < 4; ++ni) bb[ni] = bias[n0 + wc * 64 + ni * 16 + li];

    if (MODE == 0) {
        __syncthreads();                                   // K-loop LDS reads done
        if (VDIRECT && n0 >= 2048) {
            const int h = (n0 - 2048 + wc * 64) >> 6;
            const int b = m0 >> 11;
            const int tb = (m0 & 2047) + wr * 64;
            unsigned short* vstg = smem + wave * 2560;     // [64][40] padded
            #pragma unroll
            for (int mp = 0; mp < 2; ++mp) {               // mi pairs -> 32-t chunks
                #pragma unroll
                for (int mh = 0; mh < 2; ++mh) {
                    const int mi = mp * 2 + mh;
                    #pragma unroll
                    for (int ni = 0; ni < 4; ++ni)
                        #pragma unroll
                        for (int r = 0; r < 4; ++r)
                            vstg[(ni * 16 + li) * 40 + mh * 16 + g * 4 + r]
                                = f2bf(acc[mi][ni][r] + bb[ni]);
                }
                __builtin_amdgcn_wave_barrier();           // per-wave region; DS in-order
                uint4 w0 = *(const uint4*)&vstg[lane * 40];
                uint4 w1 = *(const uint4*)&vstg[lane * 40 + 8];
                uint4 w2 = *(const uint4*)&vstg[lane * 40 + 16];
                uint4 w3 = *(const uint4*)&vstg[lane * 40 + 24];
                unsigned short* dp = vTout
                    + (((size_t)(b * 16 + h) * 64 + lane) * 2048 + tb + mp * 32);
                *(uint4*)dp = w0; *(uint4*)&dp[8] = w1;
                *(uint4*)&dp[16] = w2; *(uint4*)&dp[24] = w3;
                __builtin_amdgcn_wave_barrier();
            }
        } else {
            unsigned short* stg = smem + wave * 1152;      // [16][72] padded
            const float qsc = (n0 < 1024) ? 0.125f * LOG2E : 1.0f;
            const int srow = lane & 15, scp = lane >> 4;
            #pragma unroll
            for (int mi = 0; mi < 4; ++mi) {
                #pragma unroll
                for (int ni = 0; ni < 4; ++ni)
                    #pragma unroll
                    for (int r = 0; r < 4; ++r)
                        stg[(g * 4 + r) * 72 + ni * 16 + li] = f2bf((acc[mi][ni][r] + bb[ni]) * qsc);
                __builtin_amdgcn_wave_barrier();
                uint4 w0 = *(const uint4*)&stg[srow * 72 + scp * 16];
                uint4 w1 = *(const uint4*)&stg[srow * 72 + scp * 16 + 8];
                unsigned short* dst = &outB[(size_t)(m0 + wr * 64 + mi * 16 + srow) * N
                                            + n0 + wc * 64 + scp * 16];
                *(uint4*)dst = w0;
                *(uint4*)&dst[8] = w1;
                __builtin_amdgcn_wave_barrier();
            }
        }
    } else {
        #pragma unroll
        for (int mi = 0; mi < 4; ++mi)
            #pragma unroll
            for (int ni = 0; ni < 4; ++ni) {
                const int col = n0 + wc * 64 + ni * 16 + li;
                #pragma unroll
                for (int r = 0; r < 4; ++r)
                    outF[(size_t)(m0 + wr * 64 + mi * 16 + g * 4 + r) * N + col]
                        = acc[mi][ni][r] + bb[ni];
            }
    }
}

// ================= 256x256 8-phase QKV GEMM (T2+T3+T4+T5, counted vmcnt(6)) =================
// BM=BN=256, BK=64, 8 waves (2M x 4N), 512 threads. LDS = 2 dbuf x (A 32KB + B 32KB) = 128KB.
// K-loop schedule = round-2 form (measured 71.8us) — restored verbatim after r3/r4
// restructures both regressed. Round-5 single change: n-major XCD chunking (below).
// Stage schedule per iter i (K-tiles 2i->buf0, 2i+1->buf1):
//   P1: buf1.A-h1 (kt 2i+1)   P2: buf0.B-h0 (kt 2i+2)  P3: buf0.B-h1  P4: buf0.A-h0 + vmcnt(6)
//   P5: buf0.A-h1 (kt 2i+2)   P6: buf1.B-h0 (kt 2i+3)  P7: buf1.B-h1  P8: buf1.A-h0 + vmcnt(6)
// vmcnt(6) = 3 half-tiles (2 loads/lane each) in flight; proves the buffer read next is landed.
// vmcnt counting robust to compiler-inserted VMEM: extra ops only make waits drain more.

// stage one interleaved half-tile (16KB): 2 chunks/wave, linear LDS dest, inverse-XOR global src
__device__ __forceinline__ void stage_half64(const unsigned short* g0, int ldk,
                                             unsigned short* l0, int half) {
    const int wave = threadIdx.x >> 6, lane = threadIdx.x & 63;
    #pragma unroll
    for (int s = 0; s < 2; ++s) {
        const int h = wave * 2 + s;                        // 0..15
        const int rowbase = (h >> 3) * 128 + half * 64 + (h & 7) * 8;
        const int row = rowbase + (lane >> 3);
        const int csrc = (lane & 7) ^ (row & 7);
        gll16(g0 + (size_t)row * ldk + csrc * 8, l0 + rowbase * 64 + lane * 8);
    }
}

#define G2_CLOSE   __builtin_amdgcn_s_barrier()
#define G2_CLOSE6  do { asm volatile("s_waitcnt vmcnt(6)" ::: "memory"); \
                        __builtin_amdgcn_s_barrier(); } while (0)
#define G2_CLOSE0  do { asm volatile("s_waitcnt vmcnt(0)" ::: "memory"); \
                        __builtin_amdgcn_s_barrier(); } while (0)

#define G2_PHASE(ASB, BSB, MP, STAGE_STMT, CLOSE_STMT) do {                      \
    if ((MP) == 0) {                                                             \
        _Pragma("unroll") for (int ni_ = 0; ni_ < 4; ++ni_) {                    \
            bfr[ni_][0] = *(const bf16x8*)&(BSB)[boff[ni_][0]];                  \
            bfr[ni_][1] = *(const bf16x8*)&(BSB)[boff[ni_][1]];                  \
        }                                                                        \
    }                                                                            \
    bf16x8 af00 = *(const bf16x8*)&(ASB)[aoff[2 * (MP)][0]];                     \
    bf16x8 af01 = *(const bf16x8*)&(ASB)[aoff[2 * (MP)][1]];                     \
    bf16x8 af10 = *(const bf16x8*)&(ASB)[aoff[2 * (MP) + 1][0]];                 \
    bf16x8 af11 = *(const bf16x8*)&(ASB)[aoff[2 * (MP) + 1][1]];                 \
    STAGE_STMT;                                                                  \
    __builtin_amdgcn_sched_barrier(0);  /* pin stage issue inside its phase */   \
    __builtin_amdgcn_s_barrier();                                                \
    asm volatile("s_waitcnt lgkmcnt(0)" ::: "memory");                           \
    __builtin_amdgcn_sched_barrier(0);                                           \
    __builtin_amdgcn_s_setprio(1);                                               \
    _Pragma("unroll") for (int ni_ = 0; ni_ < 4; ++ni_) {                        \
        acc[2 * (MP)][ni_]     = MFMA(af00, bfr[ni_][0], acc[2 * (MP)][ni_]);    \
        acc[2 * (MP)][ni_]     = MFMA(af01, bfr[ni_][1], acc[2 * (MP)][ni_]);    \
        acc[2 * (MP) + 1][ni_] = MFMA(af10, bfr[ni_][0], acc[2 * (MP) + 1][ni_]);\
        acc[2 * (MP) + 1][ni_] = MFMA(af11, bfr[ni_][1], acc[2 * (MP) + 1][ni_]);\
    }                                                                            \
    __builtin_amdgcn_s_setprio(0);                                               \
    CLOSE_STMT;                                                                  \
  } while (0)

#define G2_KTILE(ASB, BSB, S1, S2, S3, S4, C4) do {                              \
    bf16x8 bfr[4][2];                                                            \
    G2_PHASE(ASB, BSB, 0, S1, G2_CLOSE);                                         \
    G2_PHASE(ASB, BSB, 1, S2, G2_CLOSE);                                         \
    G2_PHASE(ASB, BSB, 2, S3, G2_CLOSE);                                         \
    G2_PHASE(ASB, BSB, 3, S4, C4);                                               \
  } while (0)

__global__ __launch_bounds__(512, 2) void qkv_gemm256_kernel(
    const unsigned short* __restrict__ A,
    const unsigned short* __restrict__ Bt,
    const float* __restrict__ bias,
    unsigned short* __restrict__ outB,
    unsigned short* __restrict__ vTout)
{
    constexpr int Kc = 1024, Nc = 3072;
    constexpr int NI = (Kc / 64) / 2;                      // 8 iterations, 2 K-tiles each
    __shared__ __align__(16) unsigned short smem[65536];   // 128 KB

    const int tid = threadIdx.x;
    const int wave = tid >> 6, lane = tid & 63;
    const int wr = wave >> 2, wc = wave & 3;
    const int g = lane >> 4, li = lane & 15;

    // Round-5: n-major XCD chunking. Each XCD owns 48 consecutive blocks in n-major
    // order = 1.5 B-column-panels x all m. Resident B per XCD ~0.5-1MB (L2-fit, hot);
    // A streams through L2 and is L3-served across XCDs. Bijective for 384 blocks.
    int bidx, bidy;
    {
        const int gx = gridDim.x, gy = gridDim.y;          // 12, 32
        const int nwg = gx * gy;
        int b = blockIdx.y * gx + blockIdx.x;
        if ((nwg & 7) == 0 && gy == 32) {
            const int per = nwg >> 3;                      // 48 blocks per XCD
            const int lin = (b & 7) * per + (b >> 3);      // n-major linear id
            bidx = lin >> 5;                               // lin / 32
            bidy = lin & 31;                               // lin % 32
        } else { bidy = blockIdx.y; bidx = blockIdx.x; }
    }
    const int m0 = bidy * 256, n0 = bidx * 256;

    unsigned short* As0 = smem;
    unsigned short* Bs0 = smem + 16384;
    unsigned short* As1 = smem + 32768;
    unsigned short* Bs1 = smem + 49152;

    const unsigned short* Ag = A  + (size_t)m0 * Kc;
    const unsigned short* Bg = Bt + (size_t)n0 * Kc;

    // fragment LDS offsets (XOR-swizzled granules; 2-way max bank aliasing)
    int aoff[8][2], boff[4][2];
    #pragma unroll
    for (int mi = 0; mi < 8; ++mi) {
        const int R = wr * 128 + mi * 16 + li;
        #pragma unroll
        for (int kk = 0; kk < 2; ++kk)
            aoff[mi][kk] = R * 64 + (((kk * 4 + g) ^ (R & 7)) * 8);
    }
    #pragma unroll
    for (int ni = 0; ni < 4; ++ni) {
        const int R = wc * 64 + ni * 16 + li;
        #pragma unroll
        for (int kk = 0; kk < 2; ++kk)
            boff[ni][kk] = R * 64 + (((kk * 4 + g) ^ (R & 7)) * 8);
    }

    f32x4 acc[8][4] = {};

    // prologue: kt0 -> buf0 (4 halves, oldest), kt1 -> buf1 (3 halves); A1h1 at iter0-P1
    stage_half64(Bg,      Kc, Bs0, 0);
    stage_half64(Bg,      Kc, Bs0, 1);
    stage_half64(Ag,      Kc, As0, 0);
    stage_half64(Ag,      Kc, As0, 1);
    stage_half64(Bg + 64, Kc, Bs1, 0);
    stage_half64(Bg + 64, Kc, Bs1, 1);
    stage_half64(Ag + 64, Kc, As1, 0);
    asm volatile("s_waitcnt vmcnt(6)" ::: "memory");       // buf0 (oldest 8 loads) landed
    __builtin_amdgcn_s_barrier();

    #pragma unroll 1
    for (int i = 0; i < NI - 1; ++i) {
        const int kA  = (2 * i + 1) * 64;
        const int kB0 = (2 * i + 2) * 64;
        const int kB1 = (2 * i + 3) * 64;
        G2_KTILE(As0, Bs0,
                 stage_half64(Ag + kA,  Kc, As1, 1),
                 stage_half64(Bg + kB0, Kc, Bs0, 0),
                 stage_half64(Bg + kB0, Kc, Bs0, 1),
                 stage_half64(Ag + kB0, Kc, As0, 0),
                 G2_CLOSE6);
        G2_KTILE(As1, Bs1,
                 stage_half64(Ag + kB0, Kc, As0, 1),
                 stage_half64(Bg + kB1, Kc, Bs1, 0),
                 stage_half64(Bg + kB1, Kc, Bs1, 1),
                 stage_half64(Ag + kB1, Kc, As1, 0),
                 G2_CLOSE6);
    }
    // peeled last iteration: only the final A-h1 stage remains; drain at P4
    G2_KTILE(As0, Bs0,
             stage_half64(Ag + (Kc - 64), Kc, As1, 1),
             (void)0, (void)0, (void)0,
             G2_CLOSE0);
    G2_KTILE(As1, Bs1, (void)0, (void)0, (void)0, (void)0, G2_CLOSE);

    __syncthreads();                                       // LDS free for epilogue staging

    float bb[4];
    #pragma unroll
    for (int ni = 0; ni < 4; ++ni) bb[ni] = bias[n0 + wc * 64 + ni * 16 + li];

    if (n0 >= 2048) {
        // v block: wave's 64-col span = one head; write vT[bh][d][t] directly (64B/lane rows)
        const int h  = ((n0 - 2048) >> 6) + wc;
        const int b  = m0 >> 11;
        const int tb = (m0 & 2047) + wr * 128;
        unsigned short* vstg = smem + wave * 2560;         // [64][40] padded
        #pragma unroll
        for (int mp = 0; mp < 4; ++mp) {                   // mi pairs -> 32-t chunks
            #pragma unroll
            for (int mh = 0; mh < 2; ++mh) {
                const int mi = mp * 2 + mh;
                #pragma unroll
                for (int ni = 0; ni < 4; ++ni)
                    #pragma unroll
                    for (int r = 0; r < 4; ++r)
                        vstg[(ni * 16 + li) * 40 + mh * 16 + g * 4 + r]
                            = f2bf(acc[mi][ni][r] + bb[ni]);
            }
            __builtin_amdgcn_wave_barrier();               // per-wave region; DS in-order
            uint4 w0 = *(const uint4*)&vstg[lane * 40];
            uint4 w1 = *(const uint4*)&vstg[lane * 40 + 8];
            uint4 w2 = *(const uint4*)&vstg[lane * 40 + 16];
            uint4 w3 = *(const uint4*)&vstg[lane * 40 + 24];
            unsigned short* dp = vTout
                + (((size_t)(b * 16 + h) * 64 + lane) * 2048 + tb + mp * 32);
            *(uint4*)dp = w0; *(uint4*)&dp[8] = w1;
            *(uint4*)&dp[16] = w2; *(uint4*)&dp[24] = w3;
            __builtin_amdgcn_wave_barrier();
        }
    } else {
        unsigned short* stg = smem + wave * 1152;          // [16][72] padded
        const float qsc = (n0 < 1024) ? 0.125f * LOG2E : 1.0f;
        const int srow = lane & 15, scp = lane >> 4;
        #pragma unroll
        for (int mi = 0; mi < 8; ++mi) {
            #pragma unroll
            for (int ni = 0; ni < 4; ++ni)
                #pragma unroll
                for (int r = 0; r < 4; ++r)
                    stg[(g * 4 + r) * 72 + ni * 16 + li] = f2bf((acc[mi][ni][r] + bb[ni]) * qsc);
            __builtin_amdgcn_wave_barrier();
            uint4 w0 = *(const uint4*)&stg[srow * 72 + scp * 16];
            uint4 w1 = *(const uint4*)&stg[srow * 72 + scp * 16 + 8];
            unsigned short* dst = &outB[(size_t)(m0 + wr * 128 + mi * 16 + srow) * Nc
                                        + n0 + wc * 64 + scp * 16];
            *(uint4*)dst = w0;
            *(uint4*)&dst[8] = w1;
            __builtin_amdgcn_wave_barrier();
        }
    }
}

// ---------------- causal flash attention v6 (paired tiles + LDS double-buffer) ----------------
__global__ __launch_bounds__(256, 4) void flash_attn_kernel(
    const unsigned short* __restrict__ qkv,
    const unsigned short* __restrict__ vT,
    unsigned short* __restrict__ y)
{
    __shared__ __align__(16) unsigned short Ks[2][64 * 64];   // [kk][d], 8-granule swizzle
    __shared__ __align__(16) unsigned short Vt[2][64 * 64];   // [d][kk]
    __shared__ __align__(16) unsigned short Pq[4][16][40];    // per-wave P^T (sequential A/B)
    const int tid = threadIdx.x;
    const int wv = tid >> 6, lane = tid & 63;
    const int g = lane >> 4, li = lane & 15;
    const int bid = blockIdx.x;
    const int xcd = bid & 7, i = bid >> 3;
    const int bh = xcd * 8 + (i & 7);          // same-bh blocks share an XCD (L2 reuse)
    const int p  = i >> 3;                      // 0..15
    const int qtA = p, qtB = 31 - p;            // paired tiles: uniform 33 active iters
    const int b = bh >> 4, h = bh & 15;
    const size_t qrowbase = (size_t)b * 2048 * 3072 + h * 64;
    const size_t vbase = (size_t)bh * (D_ * T_);
    const unsigned short* kbase = qkv + qrowbase + 1024;

    const int rowA = qtA * 64 + wv * 16 + li;
    const int rowB = qtB * 64 + wv * 16 + li;

    bf16x8 aqA[2], aqB[2];
    #pragma unroll
    for (int kc = 0; kc < 2; ++kc) {
        aqA[kc] = *(const bf16x8*)&qkv[qrowbase + (size_t)rowA * 3072 + kc * 32 + g * 8];
        aqB[kc] = *(const bf16x8*)&qkv[qrowbase + (size_t)rowB * 3072 + kc * 32 + g * 8];
    }

    f32x4 oA[4] = {}, oB[4] = {};
    float lA = 0.f, lB = 0.f;
    const float OFS = 8.0f * LOG2E;
    const int nkb = qtB + 1;

    stage16<8>(kbase, 3072, Ks[0], wv * 2);
    stage16<8>(kbase, 3072, Ks[0], wv * 2 + 1);
    stage16<8>(vT + vbase, T_, Vt[0], wv * 2);
    stage16<8>(vT + vbase, T_, Vt[0], wv * 2 + 1);

    for (int kb = 0; kb < nkb; ++kb) {
        const int cur = kb & 1;
        __syncthreads();                       // drains cur-buffer loads; prior readers done
        if (kb + 1 < nkb) {                    // prefetch next k-block; drains at NEXT barrier
            const int kn = (kb + 1) << 6;
            const int nxt = cur ^ 1;
            stage16<8>(kbase + (size_t)kn * 3072, 3072, Ks[nxt], wv * 2);
            stage16<8>(kbase + (size_t)kn * 3072, 3072, Ks[nxt], wv * 2 + 1);
            stage16<8>(vT + vbase + kn, T_, Vt[nxt], wv * 2);
            stage16<8>(vT + vbase + kn, T_, Vt[nxt], wv * 2 + 1);
        }
        const int k0 = kb << 6;
        const bool doA = (kb <= qtA);
        const unsigned short* ksb = Ks[cur];
        const unsigned short* vtb = Vt[cur];

        #pragma unroll
        for (int half = 0; half < 2; ++half) {
            f32x4 sA[2], sB[2];
            #pragma unroll
            for (int t2 = 0; t2 < 2; ++t2) {
                const int krow = (half * 2 + t2) * 16 + li;
                bf16x8 ka0 = *(const bf16x8*)&ksb[krow * 64 + ((g       ^ (krow & 7)) * 8)];
                bf16x8 ka1 = *(const bf16x8*)&ksb[krow * 64 + (((4 + g) ^ (krow & 7)) * 8)];
                f32x4 z = {};
                z = MFMA(ka0, aqB[0], z);
                sB[t2] = MFMA(ka1, aqB[1], z);
                if (doA) {
                    f32x4 z2 = {};
                    z2 = MFMA(ka0, aqA[0], z2);
                    sA[t2] = MFMA(ka1, aqA[1], z2);
                }
            }
            bf16x8 bpA, bpB;
            {
                #pragma unroll
                for (int t2 = 0; t2 < 2; ++t2) {
                    const int kkb = k0 + (half * 2 + t2) * 16;
                    const bool diag = (kb == qtB);
                    ushort4 pw;
                    #pragma unroll
                    for (int r = 0; r < 4; ++r) {
                        float sv = sB[t2][r];
                        if (diag && (kkb + g * 4 + r > rowB)) sv = -1e30f;
                        float pp = fexp2(sv - OFS);
                        lB += pp;
                        ((unsigned short*)&pw)[r] = f2bf(pp);
                    }
                    *(ushort4*)&Pq[wv][li][t2 * 16 + g * 4] = pw;
                }
                __builtin_amdgcn_wave_barrier();
                bpB = *(const bf16x8*)&Pq[wv][li][g * 8];
                __builtin_amdgcn_wave_barrier();
            }
            if (doA) {
                #pragma unroll
                for (int t2 = 0; t2 < 2; ++t2) {
                    const int kkb = k0 + (half * 2 + t2) * 16;
                    const bool diag = (kb == qtA);
                    ushort4 pw;
                    #pragma unroll
                    for (int r = 0; r < 4; ++r) {
                        float sv = sA[t2][r];
                        if (diag && (kkb + g * 4 + r > rowA)) sv = -1e30f;
                        float pp = fexp2(sv - OFS);
                        lA += pp;
                        ((unsigned short*)&pw)[r] = f2bf(pp);
                    }
                    *(ushort4*)&Pq[wv][li][t2 * 16 + g * 4] = pw;
                }
                __builtin_amdgcn_wave_barrier();
                bpA = *(const bf16x8*)&Pq[wv][li][g * 8];
                __builtin_amdgcn_wave_barrier();
            }
            #pragma unroll
            for (int ot = 0; ot < 4; ++ot) {
                const int vrow = ot * 16 + li;
                bf16x8 av = *(const bf16x8*)&vtb[vrow * 64 + (((half * 4 + g) ^ (vrow & 7)) * 8)];
                oB[ot] = MFMA(av, bpB, oB[ot]);
                if (doA) oA[ot] = MFMA(av, bpA, oA[ot]);
            }
            __builtin_amdgcn_wave_barrier();   // Pq safe before next half
        }
    }

    #pragma unroll
    for (int t = 0; t < 2; ++t) {
        float l = t ? lB : lA;
        const f32x4* o = t ? oB : oA;
        l += __shfl_xor(l, 16, 64);
        l += __shfl_xor(l, 32, 64);
        float inv = 1.f / l;
        const int trow = (t ? rowB : rowA);
        const size_t yrow = ((size_t)(b * 2048 + trow)) * 1024 + h * 64;
        #pragma unroll
        for (int ot = 0; ot < 4; ++ot) {
            ushort4 pw;
            #pragma unroll
            for (int r = 0; r < 4; ++r)
                ((unsigned short*)&pw)[r] = f2bf(o[ot][r] * inv);
            *(ushort4*)&y[yrow + ot * 16 + g * 4] = pw;
        }
    }
}

// ---------------- driver ----------------
extern "C" void kernel_launch(void* const* d_in, const int* in_sizes, int n_in,
                              void* d_out, int out_size, void* d_ws, size_t ws_size,
                              hipStream_t stream)
{
    const float* x      = (const float*)d_in[0];
    const float* W_attn = (const float*)d_in[1];
    const float* b_attn = (const float*)d_in[2];
    const float* W_proj = (const float*)d_in[3];
    const float* b_proj = (const float*)d_in[4];
    float* out = (float*)d_out;

    char* ws = (char*)d_ws;
    size_t off = 0;
    auto alloc = [&](size_t bytes) -> void* {
        void* p = ws + off;
        off += (bytes + 255) & ~(size_t)255;
        return p;
    };
    unsigned short* xb   = (unsigned short*)alloc((size_t)BT_ * C_ * 2);
    unsigned short* Wab  = (unsigned short*)alloc((size_t)3 * C_ * C_ * 2);
    unsigned short* Wpb  = (unsigned short*)alloc((size_t)C_ * C_ * 2);
    unsigned short* qkvb = (unsigned short*)alloc((size_t)BT_ * 3 * C_ * 2);   // [B,T,3,H,D]
    unsigned short* yb   = (unsigned short*)alloc((size_t)BT_ * C_ * 2);
    const size_t vt_bytes = (size_t)BT_ * C_ * 2;
    const bool vdirect = (ws_size >= off + vt_bytes);
    unsigned short* vTb = vdirect ? (unsigned short*)alloc(vt_bytes)
                                  : xb;   // fallback: reuse xb after QKV GEMM

    prep_kernel<<<12288, 256, 0, stream>>>(x, xb, W_attn, Wab, W_proj, Wpb);

    if (vdirect) {
        qkv_gemm256_kernel<<<dim3(12, 32), 512, 0, stream>>>(
            xb, Wab, b_attn, qkvb, vTb);
    } else {
        gemm_bf16_kernel<0, 0><<<dim3(24, 64), 256, 0, stream>>>(
            xb, Wab, b_attn, nullptr, qkvb, nullptr, BT_, 3 * C_, C_);
        transpose_v_kernel<<<dim3(T_ / 64, B_ * H_), 256, 0, stream>>>(qkvb, vTb);
    }

    flash_attn_kernel<<<1024, 256, 0, stream>>>(qkvb, vTb, yb);

    gemm_bf16_kernel<1, 0><<<dim3(8, 64), 256, 0, stream>>>(
        yb, Wpb, b_proj, out, nullptr, nullptr, BT_, C_, C_);
}

// Round 6
// 256.616 us; speedup vs baseline: 1.0211x; 1.0211x over previous
//
#include <hip/hip_runtime.h>

#define B_  4
#define T_  2048
#define C_  1024
#define H_  16
#define D_  64
#define BT_ 8192

typedef __bf16 bf16x8 __attribute__((ext_vector_type(8)));
typedef float  f32x4  __attribute__((ext_vector_type(4)));

#define MFMA(a, b, c) __builtin_amdgcn_mfma_f32_16x16x32_bf16((a), (b), (c), 0, 0, 0)
#define LOG2E 1.4426950408889634f

__device__ __forceinline__ float fexp2(float x) {
#if __has_builtin(__builtin_amdgcn_exp2f)
    return __builtin_amdgcn_exp2f(x);
#else
    return __expf(x * 0.6931471805599453f);
#endif
}

__device__ __forceinline__ unsigned short f2bf(float f) {
    union { float f; unsigned u; } v; v.f = f;
    unsigned r = v.u + 0x7FFFu + ((v.u >> 16) & 1u);   // RTNE
    return (unsigned short)(r >> 16);
}

// async global->LDS, 16B per lane (m97 pattern)
__device__ __forceinline__ void gll16(const unsigned short* g, unsigned short* l) {
    __builtin_amdgcn_global_load_lds((const __attribute__((address_space(1))) void*)g,
                                     (__attribute__((address_space(3))) void*)l, 16, 0, 0);
}

// Stage one 1KB chunk (64 lanes x 16B): GPR 16B-granules per row, XOR-swizzled.
template <int GPR>
__device__ __forceinline__ void stage16(const unsigned short* grow0, size_t stride_us,
                                        unsigned short* lds, int chunk) {
    const int lane = threadIdx.x & 63;
    const int gidx = chunk * 64 + lane;
    const int row  = gidx / GPR, c = gidx % GPR;
    const int csrc = c ^ (row & (GPR - 1));
    gll16(grow0 + (size_t)row * stride_us + csrc * 8, lds + gidx * 8);
}

// ---------------- fused prep: x->bf16 convert + both weight transposes ----------------
// blocks [0,8192): convert; [8192,11264): W_attn^T; [11264,12288): W_proj^T
__global__ __launch_bounds__(256) void prep_kernel(const float* __restrict__ x,
                                                   unsigned short* __restrict__ xb,
                                                   const float* __restrict__ Wa,
                                                   unsigned short* __restrict__ Wab,
                                                   const float* __restrict__ Wp,
                                                   unsigned short* __restrict__ Wpb) {
    __shared__ float tile[32][33];
    const int bid = blockIdx.x;
    if (bid < 8192) {
        int i = bid * 1024 + threadIdx.x * 4;
        float4 v = *(const float4*)&x[i];
        ushort4 o;
        o.x = f2bf(v.x); o.y = f2bf(v.y); o.z = f2bf(v.z); o.w = f2bf(v.w);
        *(ushort4*)&xb[i] = o;
        return;
    }
    const float* in; unsigned short* out; int N, t;
    if (bid < 11264) { t = bid - 8192;  in = Wa; out = Wab; N = 3072; }
    else             { t = bid - 11264; in = Wp; out = Wpb; N = 1024; }
    const int n0 = (t % (N / 32)) * 32, k0 = (t / (N / 32)) * 32;   // K=1024
    const int tr = threadIdx.x >> 3, tc = (threadIdx.x & 7) * 4;
    float4 v = *(const float4*)&in[(size_t)(k0 + tr) * N + n0 + tc];
    tile[tr][tc + 0] = v.x; tile[tr][tc + 1] = v.y;
    tile[tr][tc + 2] = v.z; tile[tr][tc + 3] = v.w;
    __syncthreads();
    ushort4 o;
    o.x = f2bf(tile[tc + 0][tr]);
    o.y = f2bf(tile[tc + 1][tr]);
    o.z = f2bf(tile[tc + 2][tr]);
    o.w = f2bf(tile[tc + 3][tr]);
    *(ushort4*)&out[(size_t)(n0 + tr) * 1024 + k0 + tc] = o;
}

// ---------------- fallback: transpose v-section of qkv -> vT [BH,D,T] ----------------
__global__ __launch_bounds__(256) void transpose_v_kernel(const unsigned short* __restrict__ qkv,
                                                          unsigned short* __restrict__ vT) {
    __shared__ unsigned short tile[64][65];
    const int bh = blockIdx.y;
    const int b = bh >> 4, h = bh & 15;
    const int t0 = blockIdx.x * 64;
    const size_t src = (size_t)b * 2048 * 3072 + 2048 + h * 64;
    const size_t dbase = (size_t)bh * (T_ * D_);
    const int r = threadIdx.x >> 2, c = (threadIdx.x & 3) * 16;
    uint4 a0 = *(const uint4*)&qkv[src + (size_t)(t0 + r) * 3072 + c];
    uint4 a1 = *(const uint4*)&qkv[src + (size_t)(t0 + r) * 3072 + c + 8];
    const unsigned short* ap = (const unsigned short*)&a0;
    #pragma unroll
    for (int i = 0; i < 8; ++i) tile[r][c + i] = ap[i];
    ap = (const unsigned short*)&a1;
    #pragma unroll
    for (int i = 0; i < 8; ++i) tile[r][c + 8 + i] = ap[i];
    __syncthreads();
    unsigned short tmp[16];
    #pragma unroll
    for (int i = 0; i < 16; ++i) tmp[i] = tile[c + i][r];
    *(uint4*)&vT[dbase + (size_t)r * T_ + t0 + c]     = *(uint4*)&tmp[0];
    *(uint4*)&vT[dbase + (size_t)r * T_ + t0 + c + 8] = *(uint4*)&tmp[8];
}

// ---------------- 128x128 bf16 MFMA GEMM (m97 staging) — kept for proj + fallback ----------------
template <int MODE, int VDIRECT>
__global__ __launch_bounds__(256) void gemm_bf16_kernel(
    const unsigned short* __restrict__ A,
    const unsigned short* __restrict__ Bt,
    const float* __restrict__ bias,
    float* __restrict__ outF,
    unsigned short* __restrict__ outB,
    unsigned short* __restrict__ vTout,
    int M, int N, int K)
{
    __shared__ __align__(16) unsigned short smem[(MODE == 0 && VDIRECT) ? 10240 : 8192];
    unsigned short* As = smem;          // [128][32], swizzled granules
    unsigned short* Bs = smem + 4096;
    const int tid = threadIdx.x;
    const int wave = tid >> 6, lane = tid & 63;
    const int wr = wave >> 1, wc = wave & 1;
    const int g = lane >> 4, li = lane & 15;
    const int m0 = blockIdx.y * 128, n0 = blockIdx.x * 128;

    f32x4 acc[4][4] = {};

    for (int k0 = 0; k0 < K; k0 += 32) {
        __syncthreads();
        stage16<4>(A  + (size_t)m0 * K + k0, K, As, wave * 2);
        stage16<4>(A  + (size_t)m0 * K + k0, K, As, wave * 2 + 1);
        stage16<4>(Bt + (size_t)n0 * K + k0, K, Bs, wave * 2);
        stage16<4>(Bt + (size_t)n0 * K + k0, K, Bs, wave * 2 + 1);
        __syncthreads();
        bf16x8 af[4], bfr[4];
        #pragma unroll
        for (int mi = 0; mi < 4; ++mi) {
            const int row = wr * 64 + mi * 16 + li;
            af[mi] = *(const bf16x8*)&As[row * 32 + ((g ^ (row & 3)) * 8)];
        }
        #pragma unroll
        for (int ni = 0; ni < 4; ++ni) {
            const int row = wc * 64 + ni * 16 + li;
            bfr[ni] = *(const bf16x8*)&Bs[row * 32 + ((g ^ (row & 3)) * 8)];
        }
        #pragma unroll
        for (int mi = 0; mi < 4; ++mi)
            #pragma unroll
            for (int ni = 0; ni < 4; ++ni)
                acc[mi][ni] = MFMA(af[mi], bfr[ni], acc[mi][ni]);
    }

    float bb[4];
    #pragma unroll
    for (int ni = 0; ni < 4; ++ni) bb[ni] = bias[n0 + wc * 64 + ni * 16 + li];

    if (MODE == 0) {
        __syncthreads();                                   // K-loop LDS reads done
        if (VDIRECT && n0 >= 2048) {
            const int h = (n0 - 2048 + wc * 64) >> 6;
            const int b = m0 >> 11;
            const int tb = (m0 & 2047) + wr * 64;
            unsigned short* vstg = smem + wave * 2560;     // [64][40] padded
            #pragma unroll
            for (int mp = 0; mp < 2; ++mp) {               // mi pairs -> 32-t chunks
                #pragma unroll
                for (int mh = 0; mh < 2; ++mh) {
                    const int mi = mp * 2 + mh;
                    #pragma unroll
                    for (int ni = 0; ni < 4; ++ni)
                        #pragma unroll
                        for (int r = 0; r < 4; ++r)
                            vstg[(ni * 16 + li) * 40 + mh * 16 + g * 4 + r]
                                = f2bf(acc[mi][ni][r] + bb[ni]);
                }
                __builtin_amdgcn_wave_barrier();           // per-wave region; DS in-order
                uint4 w0 = *(const uint4*)&vstg[lane * 40];
                uint4 w1 = *(const uint4*)&vstg[lane * 40 + 8];
                uint4 w2 = *(const uint4*)&vstg[lane * 40 + 16];
                uint4 w3 = *(const uint4*)&vstg[lane * 40 + 24];
                unsigned short* dp = vTout
                    + (((size_t)(b * 16 + h) * 64 + lane) * 2048 + tb + mp * 32);
                *(uint4*)dp = w0; *(uint4*)&dp[8] = w1;
                *(uint4*)&dp[16] = w2; *(uint4*)&dp[24] = w3;
                __builtin_amdgcn_wave_barrier();
            }
        } else {
            unsigned short* stg = smem + wave * 1152;      // [16][72] padded
            const float qsc = (n0 < 1024) ? 0.125f * LOG2E : 1.0f;
            const int srow = lane & 15, scp = lane >> 4;
            #pragma unroll
            for (int mi = 0; mi < 4; ++mi) {
                #pragma unroll
                for (int ni = 0; ni < 4; ++ni)
                    #pragma unroll
                    for (int r = 0; r < 4; ++r)
                        stg[(g * 4 + r) * 72 + ni * 16 + li] = f2bf((acc[mi][ni][r] + bb[ni]) * qsc);
                __builtin_amdgcn_wave_barrier();
                uint4 w0 = *(const uint4*)&stg[srow * 72 + scp * 16];
                uint4 w1 = *(const uint4*)&stg[srow * 72 + scp * 16 + 8];
                unsigned short* dst = &outB[(size_t)(m0 + wr * 64 + mi * 16 + srow) * N
                                            + n0 + wc * 64 + scp * 16];
                *(uint4*)dst = w0;
                *(uint4*)&dst[8] = w1;
                __builtin_amdgcn_wave_barrier();
            }
        }
    } else {
        #pragma unroll
        for (int mi = 0; mi < 4; ++mi)
            #pragma unroll
            for (int ni = 0; ni < 4; ++ni) {
                const int col = n0 + wc * 64 + ni * 16 + li;
                #pragma unroll
                for (int r = 0; r < 4; ++r)
                    outF[(size_t)(m0 + wr * 64 + mi * 16 + g * 4 + r) * N + col]
                        = acc[mi][ni][r] + bb[ni];
            }
    }
}

// ========== 256x256 8-phase QKV GEMM, SINGLE-buffer ring staging (64KB LDS, 2 blk/CU) ==========
// BM=BN=256, BK=64, 8 waves (2M x 4N), 512 threads. LDS = A 32KB + B 32KB = 64KB -> 2 blocks/CU,
// all 384 blocks co-resident (no 2nd scheduling round; cross-block overlap hides barrier drains).
// Phase structure/gates/frag reads = round-2 form (71.8us proven). Tile u+1 stages into regions
// of the SAME buffer already consumed by tile u:
//   B fully read at u.P1 top; A quarter q (rows q*32..+31 and 128+q*32..+31) read at u.P(q+1) top.
// Per-phase stage slots (steady): u.P1:[A(u).q3]  u.P2:[A(u+1).q0, B(u+1).h0, B(u+1).h1]
//                                 u.P3:[A(u+1).q1]  u.P4:[A(u+1).q2]
// Ledger (simulated): steady outstanding 7 max; closes P1:vmcnt(2) P2:vmcnt(6) P3:vmcnt(6)
// P4:vmcnt(2); every load >=2 phases flight; every overwrite's prior readers drained >=1 barrier
// earlier. Peel tile15: closes 2/1/0/plain. vmcnt robust to compiler VMEM (extra ops only
// drain more).

// stage one interleaved half-tile (16KB): 2 chunks/wave, linear LDS dest, inverse-XOR global src
__device__ __forceinline__ void stage_half64(const unsigned short* g0, int ldk,
                                             unsigned short* l0, int half) {
    const int wave = threadIdx.x >> 6, lane = threadIdx.x & 63;
    #pragma unroll
    for (int s = 0; s < 2; ++s) {
        const int h = wave * 2 + s;                        // 0..15
        const int rowbase = (h >> 3) * 128 + half * 64 + (h & 7) * 8;
        const int row = rowbase + (lane >> 3);
        const int csrc = (lane & 7) ^ (row & 7);
        gll16(g0 + (size_t)row * ldk + csrc * 8, l0 + rowbase * 64 + lane * 8);
    }
}

// stage one A-quarter (8KB, 1 load/lane): rows {q*32..+31} U {128+q*32..+31}
__device__ __forceinline__ void stage_q(const unsigned short* g0, int ldk,
                                        unsigned short* l0, int q) {
    const int wave = threadIdx.x >> 6, lane = threadIdx.x & 63;
    const int rowbase = (wave >> 2) * 128 + q * 32 + (wave & 3) * 8;
    const int row = rowbase + (lane >> 3);
    const int csrc = (lane & 7) ^ (row & 7);
    gll16(g0 + (size_t)row * ldk + csrc * 8, l0 + rowbase * 64 + lane * 8);
}

#define G2_CLOSE   __builtin_amdgcn_s_barrier()
#define G2_CLOSEN(N) do { asm volatile("s_waitcnt vmcnt(" #N ")" ::: "memory"); \
                          __builtin_amdgcn_s_barrier(); } while (0)

#define G2_PHASE(MP, STAGE_STMT, CLOSE_STMT) do {                                \
    if ((MP) == 0) {                                                             \
        _Pragma("unroll") for (int ni_ = 0; ni_ < 4; ++ni_) {                    \
            bfr[ni_][0] = *(const bf16x8*)&Bs[boff[ni_][0]];                     \
            bfr[ni_][1] = *(const bf16x8*)&Bs[boff[ni_][1]];                     \
        }                                                                        \
    }                                                                            \
    bf16x8 af00 = *(const bf16x8*)&As[aoff[2 * (MP)][0]];                        \
    bf16x8 af01 = *(const bf16x8*)&As[aoff[2 * (MP)][1]];                        \
    bf16x8 af10 = *(const bf16x8*)&As[aoff[2 * (MP) + 1][0]];                    \
    bf16x8 af11 = *(const bf16x8*)&As[aoff[2 * (MP) + 1][1]];                    \
    STAGE_STMT;                                                                  \
    __builtin_amdgcn_sched_barrier(0);  /* pin stage issue inside its phase */   \
    __builtin_amdgcn_s_barrier();                                                \
    asm volatile("s_waitcnt lgkmcnt(0)" ::: "memory");                           \
    __builtin_amdgcn_sched_barrier(0);                                           \
    __builtin_amdgcn_s_setprio(1);                                               \
    _Pragma("unroll") for (int ni_ = 0; ni_ < 4; ++ni_) {                        \
        acc[2 * (MP)][ni_]     = MFMA(af00, bfr[ni_][0], acc[2 * (MP)][ni_]);    \
        acc[2 * (MP)][ni_]     = MFMA(af01, bfr[ni_][1], acc[2 * (MP)][ni_]);    \
        acc[2 * (MP) + 1][ni_] = MFMA(af10, bfr[ni_][0], acc[2 * (MP) + 1][ni_]);\
        acc[2 * (MP) + 1][ni_] = MFMA(af11, bfr[ni_][1], acc[2 * (MP) + 1][ni_]);\
    }                                                                            \
    __builtin_amdgcn_s_setprio(0);                                               \
    CLOSE_STMT;                                                                  \
  } while (0)

#define G2_KTILE(S1, S2, S3, S4, C1, C2, C3, C4) do {                            \
    bf16x8 bfr[4][2];                                                            \
    G2_PHASE(0, S1, C1);                                                         \
    G2_PHASE(1, S2, C2);                                                         \
    G2_PHASE(2, S3, C3);                                                         \
    G2_PHASE(3, S4, C4);                                                         \
  } while (0)

__global__ __launch_bounds__(512, 2) void qkv_gemm256_kernel(
    const unsigned short* __restrict__ A,
    const unsigned short* __restrict__ Bt,
    const float* __restrict__ bias,
    unsigned short* __restrict__ outB,
    unsigned short* __restrict__ vTout)
{
    constexpr int Kc = 1024, Nc = 3072;
    constexpr int NT = Kc / 64;                            // 16 K-tiles
    __shared__ __align__(16) unsigned short smem[32768];   // 64 KB

    const int tid = threadIdx.x;
    const int wave = tid >> 6, lane = tid & 63;
    const int wr = wave >> 2, wc = wave & 3;
    const int g = lane >> 4, li = lane & 15;

    // bijective XCD-chunked swizzle (r2 form, m-major): each XCD gets 4 m-rows x all n
    int bidx, bidy;
    {
        const int gx = gridDim.x, gy = gridDim.y;
        int b = blockIdx.y * gx + blockIdx.x;
        if ((gy & 7) == 0) {
            const int gy8 = gy >> 3;
            const int k = b >> 3;
            bidy = (b & 7) * gy8 + k / gx;
            bidx = k - (k / gx) * gx;
        } else { bidy = blockIdx.y; bidx = blockIdx.x; }
    }
    const int m0 = bidy * 256, n0 = bidx * 256;

    unsigned short* As = smem;
    unsigned short* Bs = smem + 16384;

    const unsigned short* Ag = A  + (size_t)m0 * Kc;
    const unsigned short* Bg = Bt + (size_t)n0 * Kc;

    // fragment LDS offsets (XOR-swizzled granules; 2-way max bank aliasing)
    int aoff[8][2], boff[4][2];
    #pragma unroll
    for (int mi = 0; mi < 8; ++mi) {
        const int R = wr * 128 + mi * 16 + li;
        #pragma unroll
        for (int kk = 0; kk < 2; ++kk)
            aoff[mi][kk] = R * 64 + (((kk * 4 + g) ^ (R & 7)) * 8);
    }
    #pragma unroll
    for (int ni = 0; ni < 4; ++ni) {
        const int R = wc * 64 + ni * 16 + li;
        #pragma unroll
        for (int kk = 0; kk < 2; ++kk)
            boff[ni][kk] = R * 64 + (((kk * 4 + g) ^ (R & 7)) * 8);
    }

    f32x4 acc[8][4] = {};

    // prologue: tile0 B full + A q0-q2 (q3 staged at tile0.P1 per steady schedule)
    stage_half64(Bg, Kc, Bs, 0);
    stage_half64(Bg, Kc, Bs, 1);
    stage_q(Ag, Kc, As, 0);
    stage_q(Ag, Kc, As, 1);
    stage_q(Ag, Kc, As, 2);
    asm volatile("s_waitcnt vmcnt(0)" ::: "memory");
    __builtin_amdgcn_s_barrier();

    #pragma unroll 1
    for (int u = 0; u < NT - 1; ++u) {
        const unsigned short* Au = Ag + u * 64;
        const unsigned short* An = Au + 64;
        const unsigned short* Bn = Bg + (u + 1) * 64;
        G2_KTILE(
            stage_q(Au, Kc, As, 3),
            (stage_q(An, Kc, As, 0),
             stage_half64(Bn, Kc, Bs, 0),
             stage_half64(Bn, Kc, Bs, 1)),
            stage_q(An, Kc, As, 1),
            stage_q(An, Kc, As, 2),
            G2_CLOSEN(2), G2_CLOSEN(6), G2_CLOSEN(6), G2_CLOSEN(2));
    }
    // peeled last tile: only its own q3 fill; drain 2/1/0/plain
    G2_KTILE(
        stage_q(Ag + (NT - 1) * 64, Kc, As, 3),
        (void)0, (void)0, (void)0,
        G2_CLOSEN(2), G2_CLOSEN(1), G2_CLOSEN(0), G2_CLOSE);

    __syncthreads();                                       // LDS free for epilogue staging

    float bb[4];
    #pragma unroll
    for (int ni = 0; ni < 4; ++ni) bb[ni] = bias[n0 + wc * 64 + ni * 16 + li];

    if (n0 >= 2048) {
        // v block: wave's 64-col span = one head; write vT[bh][d][t] directly (64B/lane rows)
        const int h  = ((n0 - 2048) >> 6) + wc;
        const int b  = m0 >> 11;
        const int tb = (m0 & 2047) + wr * 128;
        unsigned short* vstg = smem + wave * 2560;         // [64][40] padded
        #pragma unroll
        for (int mp = 0; mp < 4; ++mp) {                   // mi pairs -> 32-t chunks
            #pragma unroll
            for (int mh = 0; mh < 2; ++mh) {
                const int mi = mp * 2 + mh;
                #pragma unroll
                for (int ni = 0; ni < 4; ++ni)
                    #pragma unroll
                    for (int r = 0; r < 4; ++r)
                        vstg[(ni * 16 + li) * 40 + mh * 16 + g * 4 + r]
                            = f2bf(acc[mi][ni][r] + bb[ni]);
            }
            __builtin_amdgcn_wave_barrier();               // per-wave region; DS in-order
            uint4 w0 = *(const uint4*)&vstg[lane * 40];
            uint4 w1 = *(const uint4*)&vstg[lane * 40 + 8];
            uint4 w2 = *(const uint4*)&vstg[lane * 40 + 16];
            uint4 w3 = *(const uint4*)&vstg[lane * 40 + 24];
            unsigned short* dp = vTout
                + (((size_t)(b * 16 + h) * 64 + lane) * 2048 + tb + mp * 32);
            *(uint4*)dp = w0; *(uint4*)&dp[8] = w1;
            *(uint4*)&dp[16] = w2; *(uint4*)&dp[24] = w3;
            __builtin_amdgcn_wave_barrier();
        }
    } else {
        unsigned short* stg = smem + wave * 1152;          // [16][72] padded
        const float qsc = (n0 < 1024) ? 0.125f * LOG2E : 1.0f;
        const int srow = lane & 15, scp = lane >> 4;
        #pragma unroll
        for (int mi = 0; mi < 8; ++mi) {
            #pragma unroll
            for (int ni = 0; ni < 4; ++ni)
                #pragma unroll
                for (int r = 0; r < 4; ++r)
                    stg[(g * 4 + r) * 72 + ni * 16 + li] = f2bf((acc[mi][ni][r] + bb[ni]) * qsc);
            __builtin_amdgcn_wave_barrier();
            uint4 w0 = *(const uint4*)&stg[srow * 72 + scp * 16];
            uint4 w1 = *(const uint4*)&stg[srow * 72 + scp * 16 + 8];
            unsigned short* dst = &outB[(size_t)(m0 + wr * 128 + mi * 16 + srow) * Nc
                                        + n0 + wc * 64 + scp * 16];
            *(uint4*)dst = w0;
            *(uint4*)&dst[8] = w1;
            __builtin_amdgcn_wave_barrier();
        }
    }
}

// ---------------- causal flash attention v6 (paired tiles + LDS double-buffer) ----------------
__global__ __launch_bounds__(256, 4) void flash_attn_kernel(
    const unsigned short* __restrict__ qkv,
    const unsigned short* __restrict__ vT,
    unsigned short* __restrict__ y)
{
    __shared__ __align__(16) unsigned short Ks[2][64 * 64];   // [kk][d], 8-granule swizzle
    __shared__ __align__(16) unsigned short Vt[2][64 * 64];   // [d][kk]
    __shared__ __align__(16) unsigned short Pq[4][16][40];    // per-wave P^T (sequential A/B)
    const int tid = threadIdx.x;
    const int wv = tid >> 6, lane = tid & 63;
    const int g = lane >> 4, li = lane & 15;
    const int bid = blockIdx.x;
    const int xcd = bid & 7, i = bid >> 3;
    const int bh = xcd * 8 + (i & 7);          // same-bh blocks share an XCD (L2 reuse)
    const int p  = i >> 3;                      // 0..15
    const int qtA = p, qtB = 31 - p;            // paired tiles: uniform 33 active iters
    const int b = bh >> 4, h = bh & 15;
    const size_t qrowbase = (size_t)b * 2048 * 3072 + h * 64;
    const size_t vbase = (size_t)bh * (D_ * T_);
    const unsigned short* kbase = qkv + qrowbase + 1024;

    const int rowA = qtA * 64 + wv * 16 + li;
    const int rowB = qtB * 64 + wv * 16 + li;

    bf16x8 aqA[2], aqB[2];
    #pragma unroll
    for (int kc = 0; kc < 2; ++kc) {
        aqA[kc] = *(const bf16x8*)&qkv[qrowbase + (size_t)rowA * 3072 + kc * 32 + g * 8];
        aqB[kc] = *(const bf16x8*)&qkv[qrowbase + (size_t)rowB * 3072 + kc * 32 + g * 8];
    }

    f32x4 oA[4] = {}, oB[4] = {};
    float lA = 0.f, lB = 0.f;
    const float OFS = 8.0f * LOG2E;
    const int nkb = qtB + 1;

    stage16<8>(kbase, 3072, Ks[0], wv * 2);
    stage16<8>(kbase, 3072, Ks[0], wv * 2 + 1);
    stage16<8>(vT + vbase, T_, Vt[0], wv * 2);
    stage16<8>(vT + vbase, T_, Vt[0], wv * 2 + 1);

    for (int kb = 0; kb < nkb; ++kb) {
        const int cur = kb & 1;
        __syncthreads();                       // drains cur-buffer loads; prior readers done
        if (kb + 1 < nkb) {                    // prefetch next k-block; drains at NEXT barrier
            const int kn = (kb + 1) << 6;
            const int nxt = cur ^ 1;
            stage16<8>(kbase + (size_t)kn * 3072, 3072, Ks[nxt], wv * 2);
            stage16<8>(kbase + (size_t)kn * 3072, 3072, Ks[nxt], wv * 2 + 1);
            stage16<8>(vT + vbase + kn, T_, Vt[nxt], wv * 2);
            stage16<8>(vT + vbase + kn, T_, Vt[nxt], wv * 2 + 1);
        }
        const int k0 = kb << 6;
        const bool doA = (kb <= qtA);
        const unsigned short* ksb = Ks[cur];
        const unsigned short* vtb = Vt[cur];

        #pragma unroll
        for (int half = 0; half < 2; ++half) {
            f32x4 sA[2], sB[2];
            #pragma unroll
            for (int t2 = 0; t2 < 2; ++t2) {
                const int krow = (half * 2 + t2) * 16 + li;
                bf16x8 ka0 = *(const bf16x8*)&ksb[krow * 64 + ((g       ^ (krow & 7)) * 8)];
                bf16x8 ka1 = *(const bf16x8*)&ksb[krow * 64 + (((4 + g) ^ (krow & 7)) * 8)];
                f32x4 z = {};
                z = MFMA(ka0, aqB[0], z);
                sB[t2] = MFMA(ka1, aqB[1], z);
                if (doA) {
                    f32x4 z2 = {};
                    z2 = MFMA(ka0, aqA[0], z2);
                    sA[t2] = MFMA(ka1, aqA[1], z2);
                }
            }
            bf16x8 bpA, bpB;
            {
                #pragma unroll
                for (int t2 = 0; t2 < 2; ++t2) {
                    const int kkb = k0 + (half * 2 + t2) * 16;
                    const bool diag = (kb == qtB);
                    ushort4 pw;
                    #pragma unroll
                    for (int r = 0; r < 4; ++r) {
                        float sv = sB[t2][r];
                        if (diag && (kkb + g * 4 + r > rowB)) sv = -1e30f;
                        float pp = fexp2(sv - OFS);
                        lB += pp;
                        ((unsigned short*)&pw)[r] = f2bf(pp);
                    }
                    *(ushort4*)&Pq[wv][li][t2 * 16 + g * 4] = pw;
                }
                __builtin_amdgcn_wave_barrier();
                bpB = *(const bf16x8*)&Pq[wv][li][g * 8];
                __builtin_amdgcn_wave_barrier();
            }
            if (doA) {
                #pragma unroll
                for (int t2 = 0; t2 < 2; ++t2) {
                    const int kkb = k0 + (half * 2 + t2) * 16;
                    const bool diag = (kb == qtA);
                    ushort4 pw;
                    #pragma unroll
                    for (int r = 0; r < 4; ++r) {
                        float sv = sA[t2][r];
                        if (diag && (kkb + g * 4 + r > rowA)) sv = -1e30f;
                        float pp = fexp2(sv - OFS);
                        lA += pp;
                        ((unsigned short*)&pw)[r] = f2bf(pp);
                    }
                    *(ushort4*)&Pq[wv][li][t2 * 16 + g * 4] = pw;
                }
                __builtin_amdgcn_wave_barrier();
                bpA = *(const bf16x8*)&Pq[wv][li][g * 8];
                __builtin_amdgcn_wave_barrier();
            }
            #pragma unroll
            for (int ot = 0; ot < 4; ++ot) {
                const int vrow = ot * 16 + li;
                bf16x8 av = *(const bf16x8*)&vtb[vrow * 64 + (((half * 4 + g) ^ (vrow & 7)) * 8)];
                oB[ot] = MFMA(av, bpB, oB[ot]);
                if (doA) oA[ot] = MFMA(av, bpA, oA[ot]);
            }
            __builtin_amdgcn_wave_barrier();   // Pq safe before next half
        }
    }

    #pragma unroll
    for (int t = 0; t < 2; ++t) {
        float l = t ? lB : lA;
        const f32x4* o = t ? oB : oA;
        l += __shfl_xor(l, 16, 64);
        l += __shfl_xor(l, 32, 64);
        float inv = 1.f / l;
        const int trow = (t ? rowB : rowA);
        const size_t yrow = ((size_t)(b * 2048 + trow)) * 1024 + h * 64;
        #pragma unroll
        for (int ot = 0; ot < 4; ++ot) {
            ushort4 pw;
            #pragma unroll
            for (int r = 0; r < 4; ++r)
                ((unsigned short*)&pw)[r] = f2bf(o[ot][r] * inv);
            *(ushort4*)&y[yrow + ot * 16 + g * 4] = pw;
        }
    }
}

// ---------------- driver ----------------
extern "C" void kernel_launch(void* const* d_in, const int* in_sizes, int n_in,
                              void* d_out, int out_size, void* d_ws, size_t ws_size,
                              hipStream_t stream)
{
    const float* x      = (const float*)d_in[0];
    const float* W_attn = (const float*)d_in[1];
    const float* b_attn = (const float*)d_in[2];
    const float* W_proj = (const float*)d_in[3];
    const float* b_proj = (const float*)d_in[4];
    float* out = (float*)d_out;

    char* ws = (char*)d_ws;
    size_t off = 0;
    auto alloc = [&](size_t bytes) -> void* {
        void* p = ws + off;
        off += (bytes + 255) & ~(size_t)255;
        return p;
    };
    unsigned short* xb   = (unsigned short*)alloc((size_t)BT_ * C_ * 2);
    unsigned short* Wab  = (unsigned short*)alloc((size_t)3 * C_ * C_ * 2);
    unsigned short* Wpb  = (unsigned short*)alloc((size_t)C_ * C_ * 2);
    unsigned short* qkvb = (unsigned short*)alloc((size_t)BT_ * 3 * C_ * 2);   // [B,T,3,H,D]
    unsigned short* yb   = (unsigned short*)alloc((size_t)BT_ * C_ * 2);
    const size_t vt_bytes = (size_t)BT_ * C_ * 2;
    const bool vdirect = (ws_size >= off + vt_bytes);
    unsigned short* vTb = vdirect ? (unsigned short*)alloc(vt_bytes)
                                  : xb;   // fallback: reuse xb after QKV GEMM

    prep_kernel<<<12288, 256, 0, stream>>>(x, xb, W_attn, Wab, W_proj, Wpb);

    if (vdirect) {
        qkv_gemm256_kernel<<<dim3(12, 32), 512, 0, stream>>>(
            xb, Wab, b_attn, qkvb, vTb);
    } else {
        gemm_bf16_kernel<0, 0><<<dim3(24, 64), 256, 0, stream>>>(
            xb, Wab, b_attn, nullptr, qkvb, nullptr, BT_, 3 * C_, C_);
        transpose_v_kernel<<<dim3(T_ / 64, B_ * H_), 256, 0, stream>>>(qkvb, vTb);
    }

    flash_attn_kernel<<<1024, 256, 0, stream>>>(qkvb, vTb, yb);

    gemm_bf16_kernel<1, 0><<<dim3(8, 64), 256, 0, stream>>>(
        yb, Wpb, b_proj, out, nullptr, nullptr, BT_, C_, C_);
}

// Round 7
// 248.468 us; speedup vs baseline: 1.0546x; 1.0328x over previous
//
#include <hip/hip_runtime.h>

#define B_  4
#define T_  2048
#define C_  1024
#define H_  16
#define D_  64
#define BT_ 8192

typedef __bf16 bf16x8 __attribute__((ext_vector_type(8)));
typedef float  f32x4  __attribute__((ext_vector_type(4)));

#define MFMA(a, b, c) __builtin_amdgcn_mfma_f32_16x16x32_bf16((a), (b), (c), 0, 0, 0)
#define LOG2E 1.4426950408889634f

__device__ __forceinline__ float fexp2(float x) {
#if __has_builtin(__builtin_amdgcn_exp2f)
    return __builtin_amdgcn_exp2f(x);
#else
    return __expf(x * 0.6931471805599453f);
#endif
}

// f32 -> bf16 RTNE via native HW convert (v_cvt_pk_bf16_f32). Bit-identical to the
// manual (u + 0x7FFF + odd-bit) round for finite values; compiler packs pairs.
__device__ __forceinline__ unsigned short f2bf(float f) {
    __bf16 h = (__bf16)f;
    union { __bf16 b; unsigned short u; } v; v.b = h;
    return v.u;
}

// async global->LDS, 16B per lane (m97 pattern)
__device__ __forceinline__ void gll16(const unsigned short* g, unsigned short* l) {
    __builtin_amdgcn_global_load_lds((const __attribute__((address_space(1))) void*)g,
                                     (__attribute__((address_space(3))) void*)l, 16, 0, 0);
}

// Stage one 1KB chunk (64 lanes x 16B): GPR 16B-granules per row, XOR-swizzled.
template <int GPR>
__device__ __forceinline__ void stage16(const unsigned short* grow0, size_t stride_us,
                                        unsigned short* lds, int chunk) {
    const int lane = threadIdx.x & 63;
    const int gidx = chunk * 64 + lane;
    const int row  = gidx / GPR, c = gidx % GPR;
    const int csrc = c ^ (row & (GPR - 1));
    gll16(grow0 + (size_t)row * stride_us + csrc * 8, lds + gidx * 8);
}

// ---------------- fused prep: x->bf16 convert + both weight transposes ----------------
// blocks [0,8192): convert; [8192,11264): W_attn^T; [11264,12288): W_proj^T
__global__ __launch_bounds__(256) void prep_kernel(const float* __restrict__ x,
                                                   unsigned short* __restrict__ xb,
                                                   const float* __restrict__ Wa,
                                                   unsigned short* __restrict__ Wab,
                                                   const float* __restrict__ Wp,
                                                   unsigned short* __restrict__ Wpb) {
    __shared__ float tile[32][33];
    const int bid = blockIdx.x;
    if (bid < 8192) {
        int i = bid * 1024 + threadIdx.x * 4;
        float4 v = *(const float4*)&x[i];
        ushort4 o;
        o.x = f2bf(v.x); o.y = f2bf(v.y); o.z = f2bf(v.z); o.w = f2bf(v.w);
        *(ushort4*)&xb[i] = o;
        return;
    }
    const float* in; unsigned short* out; int N, t;
    if (bid < 11264) { t = bid - 8192;  in = Wa; out = Wab; N = 3072; }
    else             { t = bid - 11264; in = Wp; out = Wpb; N = 1024; }
    const int n0 = (t % (N / 32)) * 32, k0 = (t / (N / 32)) * 32;   // K=1024
    const int tr = threadIdx.x >> 3, tc = (threadIdx.x & 7) * 4;
    float4 v = *(const float4*)&in[(size_t)(k0 + tr) * N + n0 + tc];
    tile[tr][tc + 0] = v.x; tile[tr][tc + 1] = v.y;
    tile[tr][tc + 2] = v.z; tile[tr][tc + 3] = v.w;
    __syncthreads();
    ushort4 o;
    o.x = f2bf(tile[tc + 0][tr]);
    o.y = f2bf(tile[tc + 1][tr]);
    o.z = f2bf(tile[tc + 2][tr]);
    o.w = f2bf(tile[tc + 3][tr]);
    *(ushort4*)&out[(size_t)(n0 + tr) * 1024 + k0 + tc] = o;
}

// ---------------- fallback: transpose v-section of qkv -> vT [BH,D,T] ----------------
__global__ __launch_bounds__(256) void transpose_v_kernel(const unsigned short* __restrict__ qkv,
                                                          unsigned short* __restrict__ vT) {
    __shared__ unsigned short tile[64][65];
    const int bh = blockIdx.y;
    const int b = bh >> 4, h = bh & 15;
    const int t0 = blockIdx.x * 64;
    const size_t src = (size_t)b * 2048 * 3072 + 2048 + h * 64;
    const size_t dbase = (size_t)bh * (T_ * D_);
    const int r = threadIdx.x >> 2, c = (threadIdx.x & 3) * 16;
    uint4 a0 = *(const uint4*)&qkv[src + (size_t)(t0 + r) * 3072 + c];
    uint4 a1 = *(const uint4*)&qkv[src + (size_t)(t0 + r) * 3072 + c + 8];
    const unsigned short* ap = (const unsigned short*)&a0;
    #pragma unroll
    for (int i = 0; i < 8; ++i) tile[r][c + i] = ap[i];
    ap = (const unsigned short*)&a1;
    #pragma unroll
    for (int i = 0; i < 8; ++i) tile[r][c + 8 + i] = ap[i];
    __syncthreads();
    unsigned short tmp[16];
    #pragma unroll
    for (int i = 0; i < 16; ++i) tmp[i] = tile[c + i][r];
    *(uint4*)&vT[dbase + (size_t)r * T_ + t0 + c]     = *(uint4*)&tmp[0];
    *(uint4*)&vT[dbase + (size_t)r * T_ + t0 + c + 8] = *(uint4*)&tmp[8];
}

// ---------------- 128x128 bf16 MFMA GEMM (m97 staging) — kept for proj + fallback ----------------
template <int MODE, int VDIRECT>
__global__ __launch_bounds__(256) void gemm_bf16_kernel(
    const unsigned short* __restrict__ A,
    const unsigned short* __restrict__ Bt,
    const float* __restrict__ bias,
    float* __restrict__ outF,
    unsigned short* __restrict__ outB,
    unsigned short* __restrict__ vTout,
    int M, int N, int K)
{
    __shared__ __align__(16) unsigned short smem[(MODE == 0 && VDIRECT) ? 10240 : 8192];
    unsigned short* As = smem;          // [128][32], swizzled granules
    unsigned short* Bs = smem + 4096;
    const int tid = threadIdx.x;
    const int wave = tid >> 6, lane = tid & 63;
    const int wr = wave >> 1, wc = wave & 1;
    const int g = lane >> 4, li = lane & 15;
    const int m0 = blockIdx.y * 128, n0 = blockIdx.x * 128;

    f32x4 acc[4][4] = {};

    for (int k0 = 0; k0 < K; k0 += 32) {
        __syncthreads();
        stage16<4>(A  + (size_t)m0 * K + k0, K, As, wave * 2);
        stage16<4>(A  + (size_t)m0 * K + k0, K, As, wave * 2 + 1);
        stage16<4>(Bt + (size_t)n0 * K + k0, K, Bs, wave * 2);
        stage16<4>(Bt + (size_t)n0 * K + k0, K, Bs, wave * 2 + 1);
        __syncthreads();
        bf16x8 af[4], bfr[4];
        #pragma unroll
        for (int mi = 0; mi < 4; ++mi) {
            const int row = wr * 64 + mi * 16 + li;
            af[mi] = *(const bf16x8*)&As[row * 32 + ((g ^ (row & 3)) * 8)];
        }
        #pragma unroll
        for (int ni = 0; ni < 4; ++ni) {
            const int row = wc * 64 + ni * 16 + li;
            bfr[ni] = *(const bf16x8*)&Bs[row * 32 + ((g ^ (row & 3)) * 8)];
        }
        #pragma unroll
        for (int mi = 0; mi < 4; ++mi)
            #pragma unroll
            for (int ni = 0; ni < 4; ++ni)
                acc[mi][ni] = MFMA(af[mi], bfr[ni], acc[mi][ni]);
    }

    float bb[4];
    #pragma unroll
    for (int ni = 0; ni < 4; ++ni) bb[ni] = bias[n0 + wc * 64 + ni * 16 + li];

    if (MODE == 0) {
        __syncthreads();                                   // K-loop LDS reads done
        if (VDIRECT && n0 >= 2048) {
            const int h = (n0 - 2048 + wc * 64) >> 6;
            const int b = m0 >> 11;
            const int tb = (m0 & 2047) + wr * 64;
            unsigned short* vstg = smem + wave * 2560;     // [64][40] padded
            #pragma unroll
            for (int mp = 0; mp < 2; ++mp) {               // mi pairs -> 32-t chunks
                #pragma unroll
                for (int mh = 0; mh < 2; ++mh) {
                    const int mi = mp * 2 + mh;
                    #pragma unroll
                    for (int ni = 0; ni < 4; ++ni)
                        #pragma unroll
                        for (int r = 0; r < 4; ++r)
                            vstg[(ni * 16 + li) * 40 + mh * 16 + g * 4 + r]
                                = f2bf(acc[mi][ni][r] + bb[ni]);
                }
                __builtin_amdgcn_wave_barrier();           // per-wave region; DS in-order
                uint4 w0 = *(const uint4*)&vstg[lane * 40];
                uint4 w1 = *(const uint4*)&vstg[lane * 40 + 8];
                uint4 w2 = *(const uint4*)&vstg[lane * 40 + 16];
                uint4 w3 = *(const uint4*)&vstg[lane * 40 + 24];
                unsigned short* dp = vTout
                    + (((size_t)(b * 16 + h) * 64 + lane) * 2048 + tb + mp * 32);
                *(uint4*)dp = w0; *(uint4*)&dp[8] = w1;
                *(uint4*)&dp[16] = w2; *(uint4*)&dp[24] = w3;
                __builtin_amdgcn_wave_barrier();
            }
        } else {
            unsigned short* stg = smem + wave * 1152;      // [16][72] padded
            const float qsc = (n0 < 1024) ? 0.125f * LOG2E : 1.0f;
            const int srow = lane & 15, scp = lane >> 4;
            #pragma unroll
            for (int mi = 0; mi < 4; ++mi) {
                #pragma unroll
                for (int ni = 0; ni < 4; ++ni)
                    #pragma unroll
                    for (int r = 0; r < 4; ++r)
                        stg[(g * 4 + r) * 72 + ni * 16 + li] = f2bf((acc[mi][ni][r] + bb[ni]) * qsc);
                __builtin_amdgcn_wave_barrier();
                uint4 w0 = *(const uint4*)&stg[srow * 72 + scp * 16];
                uint4 w1 = *(const uint4*)&stg[srow * 72 + scp * 16 + 8];
                unsigned short* dst = &outB[(size_t)(m0 + wr * 64 + mi * 16 + srow) * N
                                            + n0 + wc * 64 + scp * 16];
                *(uint4*)dst = w0;
                *(uint4*)&dst[8] = w1;
                __builtin_amdgcn_wave_barrier();
            }
        }
    } else {
        #pragma unroll
        for (int mi = 0; mi < 4; ++mi)
            #pragma unroll
            for (int ni = 0; ni < 4; ++ni) {
                const int col = n0 + wc * 64 + ni * 16 + li;
                #pragma unroll
                for (int r = 0; r < 4; ++r)
                    outF[(size_t)(m0 + wr * 64 + mi * 16 + g * 4 + r) * N + col]
                        = acc[mi][ni][r] + bb[ni];
            }
    }
}

// ========== 256x256 8-phase QKV GEMM, SINGLE-buffer ring staging (64KB LDS) ==========
// r6 state frozen: structural plateau at ~72us (reg budget caps 1 block/CU: 128 acc +
// ~112 VGPR = 240/512 -> 2 waves/SIMD; MFMA floor 13.8us + phase-serialized LDS stream
// + barrier skew ~= 36us/block x 1.5 rounds). See r2-r6 ledger comments.
// Per-phase stage slots (steady): u.P1:[A(u).q3]  u.P2:[A(u+1).q0, B(u+1).h0, B(u+1).h1]
//                                 u.P3:[A(u+1).q1]  u.P4:[A(u+1).q2]
// Closes P1:vmcnt(2) P2:vmcnt(6) P3:vmcnt(6) P4:vmcnt(2); peel 2/1/0/plain.

__device__ __forceinline__ void stage_half64(const unsigned short* g0, int ldk,
                                             unsigned short* l0, int half) {
    const int wave = threadIdx.x >> 6, lane = threadIdx.x & 63;
    #pragma unroll
    for (int s = 0; s < 2; ++s) {
        const int h = wave * 2 + s;                        // 0..15
        const int rowbase = (h >> 3) * 128 + half * 64 + (h & 7) * 8;
        const int row = rowbase + (lane >> 3);
        const int csrc = (lane & 7) ^ (row & 7);
        gll16(g0 + (size_t)row * ldk + csrc * 8, l0 + rowbase * 64 + lane * 8);
    }
}

// stage one A-quarter (8KB, 1 load/lane): rows {q*32..+31} U {128+q*32..+31}
__device__ __forceinline__ void stage_q(const unsigned short* g0, int ldk,
                                        unsigned short* l0, int q) {
    const int wave = threadIdx.x >> 6, lane = threadIdx.x & 63;
    const int rowbase = (wave >> 2) * 128 + q * 32 + (wave & 3) * 8;
    const int row = rowbase + (lane >> 3);
    const int csrc = (lane & 7) ^ (row & 7);
    gll16(g0 + (size_t)row * ldk + csrc * 8, l0 + rowbase * 64 + lane * 8);
}

#define G2_CLOSE   __builtin_amdgcn_s_barrier()
#define G2_CLOSEN(N) do { asm volatile("s_waitcnt vmcnt(" #N ")" ::: "memory"); \
                          __builtin_amdgcn_s_barrier(); } while (0)

#define G2_PHASE(MP, STAGE_STMT, CLOSE_STMT) do {                                \
    if ((MP) == 0) {                                                             \
        _Pragma("unroll") for (int ni_ = 0; ni_ < 4; ++ni_) {                    \
            bfr[ni_][0] = *(const bf16x8*)&Bs[boff[ni_][0]];                     \
            bfr[ni_][1] = *(const bf16x8*)&Bs[boff[ni_][1]];                     \
        }                                                                        \
    }                                                                            \
    bf16x8 af00 = *(const bf16x8*)&As[aoff[2 * (MP)][0]];                        \
    bf16x8 af01 = *(const bf16x8*)&As[aoff[2 * (MP)][1]];                        \
    bf16x8 af10 = *(const bf16x8*)&As[aoff[2 * (MP) + 1][0]];                    \
    bf16x8 af11 = *(const bf16x8*)&As[aoff[2 * (MP) + 1][1]];                    \
    STAGE_STMT;                                                                  \
    __builtin_amdgcn_sched_barrier(0);  /* pin stage issue inside its phase */   \
    __builtin_amdgcn_s_barrier();                                                \
    asm volatile("s_waitcnt lgkmcnt(0)" ::: "memory");                           \
    __builtin_amdgcn_sched_barrier(0);                                           \
    __builtin_amdgcn_s_setprio(1);                                               \
    _Pragma("unroll") for (int ni_ = 0; ni_ < 4; ++ni_) {                        \
        acc[2 * (MP)][ni_]     = MFMA(af00, bfr[ni_][0], acc[2 * (MP)][ni_]);    \
        acc[2 * (MP)][ni_]     = MFMA(af01, bfr[ni_][1], acc[2 * (MP)][ni_]);    \
        acc[2 * (MP) + 1][ni_] = MFMA(af10, bfr[ni_][0], acc[2 * (MP) + 1][ni_]);\
        acc[2 * (MP) + 1][ni_] = MFMA(af11, bfr[ni_][1], acc[2 * (MP) + 1][ni_]);\
    }                                                                            \
    __builtin_amdgcn_s_setprio(0);                                               \
    CLOSE_STMT;                                                                  \
  } while (0)

#define G2_KTILE(S1, S2, S3, S4, C1, C2, C3, C4) do {                            \
    bf16x8 bfr[4][2];                                                            \
    G2_PHASE(0, S1, C1);                                                         \
    G2_PHASE(1, S2, C2);                                                         \
    G2_PHASE(2, S3, C3);                                                         \
    G2_PHASE(3, S4, C4);                                                         \
  } while (0)

__global__ __launch_bounds__(512, 2) void qkv_gemm256_kernel(
    const unsigned short* __restrict__ A,
    const unsigned short* __restrict__ Bt,
    const float* __restrict__ bias,
    unsigned short* __restrict__ outB,
    unsigned short* __restrict__ vTout)
{
    constexpr int Kc = 1024, Nc = 3072;
    constexpr int NT = Kc / 64;                            // 16 K-tiles
    __shared__ __align__(16) unsigned short smem[32768];   // 64 KB

    const int tid = threadIdx.x;
    const int wave = tid >> 6, lane = tid & 63;
    const int wr = wave >> 2, wc = wave & 3;
    const int g = lane >> 4, li = lane & 15;

    // bijective XCD-chunked swizzle (m-major): each XCD gets 4 m-rows x all n
    int bidx, bidy;
    {
        const int gx = gridDim.x, gy = gridDim.y;
        int b = blockIdx.y * gx + blockIdx.x;
        if ((gy & 7) == 0) {
            const int gy8 = gy >> 3;
            const int k = b >> 3;
            bidy = (b & 7) * gy8 + k / gx;
            bidx = k - (k / gx) * gx;
        } else { bidy = blockIdx.y; bidx = blockIdx.x; }
    }
    const int m0 = bidy * 256, n0 = bidx * 256;

    unsigned short* As = smem;
    unsigned short* Bs = smem + 16384;

    const unsigned short* Ag = A  + (size_t)m0 * Kc;
    const unsigned short* Bg = Bt + (size_t)n0 * Kc;

    // fragment LDS offsets (XOR-swizzled granules; 2-way max bank aliasing)
    int aoff[8][2], boff[4][2];
    #pragma unroll
    for (int mi = 0; mi < 8; ++mi) {
        const int R = wr * 128 + mi * 16 + li;
        #pragma unroll
        for (int kk = 0; kk < 2; ++kk)
            aoff[mi][kk] = R * 64 + (((kk * 4 + g) ^ (R & 7)) * 8);
    }
    #pragma unroll
    for (int ni = 0; ni < 4; ++ni) {
        const int R = wc * 64 + ni * 16 + li;
        #pragma unroll
        for (int kk = 0; kk < 2; ++kk)
            boff[ni][kk] = R * 64 + (((kk * 4 + g) ^ (R & 7)) * 8);
    }

    f32x4 acc[8][4] = {};

    // prologue: tile0 B full + A q0-q2 (q3 staged at tile0.P1 per steady schedule)
    stage_half64(Bg, Kc, Bs, 0);
    stage_half64(Bg, Kc, Bs, 1);
    stage_q(Ag, Kc, As, 0);
    stage_q(Ag, Kc, As, 1);
    stage_q(Ag, Kc, As, 2);
    asm volatile("s_waitcnt vmcnt(0)" ::: "memory");
    __builtin_amdgcn_s_barrier();

    #pragma unroll 1
    for (int u = 0; u < NT - 1; ++u) {
        const unsigned short* Au = Ag + u * 64;
        const unsigned short* An = Au + 64;
        const unsigned short* Bn = Bg + (u + 1) * 64;
        G2_KTILE(
            stage_q(Au, Kc, As, 3),
            (stage_q(An, Kc, As, 0),
             stage_half64(Bn, Kc, Bs, 0),
             stage_half64(Bn, Kc, Bs, 1)),
            stage_q(An, Kc, As, 1),
            stage_q(An, Kc, As, 2),
            G2_CLOSEN(2), G2_CLOSEN(6), G2_CLOSEN(6), G2_CLOSEN(2));
    }
    // peeled last tile: only its own q3 fill; drain 2/1/0/plain
    G2_KTILE(
        stage_q(Ag + (NT - 1) * 64, Kc, As, 3),
        (void)0, (void)0, (void)0,
        G2_CLOSEN(2), G2_CLOSEN(1), G2_CLOSEN(0), G2_CLOSE);

    __syncthreads();                                       // LDS free for epilogue staging

    float bb[4];
    #pragma unroll
    for (int ni = 0; ni < 4; ++ni) bb[ni] = bias[n0 + wc * 64 + ni * 16 + li];

    if (n0 >= 2048) {
        // v block: wave's 64-col span = one head; write vT[bh][d][t] directly (64B/lane rows)
        const int h  = ((n0 - 2048) >> 6) + wc;
        const int b  = m0 >> 11;
        const int tb = (m0 & 2047) + wr * 128;
        unsigned short* vstg = smem + wave * 2560;         // [64][40] padded
        #pragma unroll
        for (int mp = 0; mp < 4; ++mp) {                   // mi pairs -> 32-t chunks
            #pragma unroll
            for (int mh = 0; mh < 2; ++mh) {
                const int mi = mp * 2 + mh;
                #pragma unroll
                for (int ni = 0; ni < 4; ++ni)
                    #pragma unroll
                    for (int r = 0; r < 4; ++r)
                        vstg[(ni * 16 + li) * 40 + mh * 16 + g * 4 + r]
                            = f2bf(acc[mi][ni][r] + bb[ni]);
            }
            __builtin_amdgcn_wave_barrier();               // per-wave region; DS in-order
            uint4 w0 = *(const uint4*)&vstg[lane * 40];
            uint4 w1 = *(const uint4*)&vstg[lane * 40 + 8];
            uint4 w2 = *(const uint4*)&vstg[lane * 40 + 16];
            uint4 w3 = *(const uint4*)&vstg[lane * 40 + 24];
            unsigned short* dp = vTout
                + (((size_t)(b * 16 + h) * 64 + lane) * 2048 + tb + mp * 32);
            *(uint4*)dp = w0; *(uint4*)&dp[8] = w1;
            *(uint4*)&dp[16] = w2; *(uint4*)&dp[24] = w3;
            __builtin_amdgcn_wave_barrier();
        }
    } else {
        unsigned short* stg = smem + wave * 1152;          // [16][72] padded
        const float qsc = (n0 < 1024) ? 0.125f * LOG2E : 1.0f;
        const int srow = lane & 15, scp = lane >> 4;
        #pragma unroll
        for (int mi = 0; mi < 8; ++mi) {
            #pragma unroll
            for (int ni = 0; ni < 4; ++ni)
                #pragma unroll
                for (int r = 0; r < 4; ++r)
                    stg[(g * 4 + r) * 72 + ni * 16 + li] = f2bf((acc[mi][ni][r] + bb[ni]) * qsc);
            __builtin_amdgcn_wave_barrier();
            uint4 w0 = *(const uint4*)&stg[srow * 72 + scp * 16];
            uint4 w1 = *(const uint4*)&stg[srow * 72 + scp * 16 + 8];
            unsigned short* dst = &outB[(size_t)(m0 + wr * 128 + mi * 16 + srow) * Nc
                                        + n0 + wc * 64 + scp * 16];
            *(uint4*)dst = w0;
            *(uint4*)&dst[8] = w1;
            __builtin_amdgcn_wave_barrier();
        }
    }
}

// ---------------- causal flash attention v7 (native bf16 cvt + MFMA setprio) ----------------
__global__ __launch_bounds__(256, 4) void flash_attn_kernel(
    const unsigned short* __restrict__ qkv,
    const unsigned short* __restrict__ vT,
    unsigned short* __restrict__ y)
{
    __shared__ __align__(16) unsigned short Ks[2][64 * 64];   // [kk][d], 8-granule swizzle
    __shared__ __align__(16) unsigned short Vt[2][64 * 64];   // [d][kk]
    __shared__ __align__(16) unsigned short Pq[4][16][40];    // per-wave P^T (sequential A/B)
    const int tid = threadIdx.x;
    const int wv = tid >> 6, lane = tid & 63;
    const int g = lane >> 4, li = lane & 15;
    const int bid = blockIdx.x;
    const int xcd = bid & 7, i = bid >> 3;
    const int bh = xcd * 8 + (i & 7);          // same-bh blocks share an XCD (L2 reuse)
    const int p  = i >> 3;                      // 0..15
    const int qtA = p, qtB = 31 - p;            // paired tiles: uniform 33 active iters
    const int b = bh >> 4, h = bh & 15;
    const size_t qrowbase = (size_t)b * 2048 * 3072 + h * 64;
    const size_t vbase = (size_t)bh * (D_ * T_);
    const unsigned short* kbase = qkv + qrowbase + 1024;

    const int rowA = qtA * 64 + wv * 16 + li;
    const int rowB = qtB * 64 + wv * 16 + li;

    bf16x8 aqA[2], aqB[2];
    #pragma unroll
    for (int kc = 0; kc < 2; ++kc) {
        aqA[kc] = *(const bf16x8*)&qkv[qrowbase + (size_t)rowA * 3072 + kc * 32 + g * 8];
        aqB[kc] = *(const bf16x8*)&qkv[qrowbase + (size_t)rowB * 3072 + kc * 32 + g * 8];
    }

    f32x4 oA[4] = {}, oB[4] = {};
    float lA = 0.f, lB = 0.f;
    const float OFS = 8.0f * LOG2E;
    const int nkb = qtB + 1;

    stage16<8>(kbase, 3072, Ks[0], wv * 2);
    stage16<8>(kbase, 3072, Ks[0], wv * 2 + 1);
    stage16<8>(vT + vbase, T_, Vt[0], wv * 2);
    stage16<8>(vT + vbase, T_, Vt[0], wv * 2 + 1);

    for (int kb = 0; kb < nkb; ++kb) {
        const int cur = kb & 1;
        __syncthreads();                       // drains cur-buffer loads; prior readers done
        if (kb + 1 < nkb) {                    // prefetch next k-block; drains at NEXT barrier
            const int kn = (kb + 1) << 6;
            const int nxt = cur ^ 1;
            stage16<8>(kbase + (size_t)kn * 3072, 3072, Ks[nxt], wv * 2);
            stage16<8>(kbase + (size_t)kn * 3072, 3072, Ks[nxt], wv * 2 + 1);
            stage16<8>(vT + vbase + kn, T_, Vt[nxt], wv * 2);
            stage16<8>(vT + vbase + kn, T_, Vt[nxt], wv * 2 + 1);
        }
        const int k0 = kb << 6;
        const bool doA = (kb <= qtA);
        const unsigned short* ksb = Ks[cur];
        const unsigned short* vtb = Vt[cur];

        #pragma unroll
        for (int half = 0; half < 2; ++half) {
            f32x4 sA[2], sB[2];
            #pragma unroll
            for (int t2 = 0; t2 < 2; ++t2) {
                const int krow = (half * 2 + t2) * 16 + li;
                bf16x8 ka0 = *(const bf16x8*)&ksb[krow * 64 + ((g       ^ (krow & 7)) * 8)];
                bf16x8 ka1 = *(const bf16x8*)&ksb[krow * 64 + (((4 + g) ^ (krow & 7)) * 8)];
                __builtin_amdgcn_s_setprio(1);
                f32x4 z = {};
                z = MFMA(ka0, aqB[0], z);
                sB[t2] = MFMA(ka1, aqB[1], z);
                if (doA) {
                    f32x4 z2 = {};
                    z2 = MFMA(ka0, aqA[0], z2);
                    sA[t2] = MFMA(ka1, aqA[1], z2);
                }
                __builtin_amdgcn_s_setprio(0);
            }
            bf16x8 bpA, bpB;
            {
                #pragma unroll
                for (int t2 = 0; t2 < 2; ++t2) {
                    const int kkb = k0 + (half * 2 + t2) * 16;
                    const bool diag = (kb == qtB);
                    ushort4 pw;
                    #pragma unroll
                    for (int r = 0; r < 4; ++r) {
                        float sv = sB[t2][r];
                        if (diag && (kkb + g * 4 + r > rowB)) sv = -1e30f;
                        float pp = fexp2(sv - OFS);
                        lB += pp;
                        ((unsigned short*)&pw)[r] = f2bf(pp);
                    }
                    *(ushort4*)&Pq[wv][li][t2 * 16 + g * 4] = pw;
                }
                __builtin_amdgcn_wave_barrier();
                bpB = *(const bf16x8*)&Pq[wv][li][g * 8];
                __builtin_amdgcn_wave_barrier();
            }
            if (doA) {
                #pragma unroll
                for (int t2 = 0; t2 < 2; ++t2) {
                    const int kkb = k0 + (half * 2 + t2) * 16;
                    const bool diag = (kb == qtA);
                    ushort4 pw;
                    #pragma unroll
                    for (int r = 0; r < 4; ++r) {
                        float sv = sA[t2][r];
                        if (diag && (kkb + g * 4 + r > rowA)) sv = -1e30f;
                        float pp = fexp2(sv - OFS);
                        lA += pp;
                        ((unsigned short*)&pw)[r] = f2bf(pp);
                    }
                    *(ushort4*)&Pq[wv][li][t2 * 16 + g * 4] = pw;
                }
                __builtin_amdgcn_wave_barrier();
                bpA = *(const bf16x8*)&Pq[wv][li][g * 8];
                __builtin_amdgcn_wave_barrier();
            }
            __builtin_amdgcn_s_setprio(1);
            #pragma unroll
            for (int ot = 0; ot < 4; ++ot) {
                const int vrow = ot * 16 + li;
                bf16x8 av = *(const bf16x8*)&vtb[vrow * 64 + (((half * 4 + g) ^ (vrow & 7)) * 8)];
                oB[ot] = MFMA(av, bpB, oB[ot]);
                if (doA) oA[ot] = MFMA(av, bpA, oA[ot]);
            }
            __builtin_amdgcn_s_setprio(0);
            __builtin_amdgcn_wave_barrier();   // Pq safe before next half
        }
    }

    #pragma unroll
    for (int t = 0; t < 2; ++t) {
        float l = t ? lB : lA;
        const f32x4* o = t ? oB : oA;
        l += __shfl_xor(l, 16, 64);
        l += __shfl_xor(l, 32, 64);
        float inv = 1.f / l;
        const int trow = (t ? rowB : rowA);
        const size_t yrow = ((size_t)(b * 2048 + trow)) * 1024 + h * 64;
        #pragma unroll
        for (int ot = 0; ot < 4; ++ot) {
            ushort4 pw;
            #pragma unroll
            for (int r = 0; r < 4; ++r)
                ((unsigned short*)&pw)[r] = f2bf(o[ot][r] * inv);
            *(ushort4*)&y[yrow + ot * 16 + g * 4] = pw;
        }
    }
}

// ---------------- driver ----------------
extern "C" void kernel_launch(void* const* d_in, const int* in_sizes, int n_in,
                              void* d_out, int out_size, void* d_ws, size_t ws_size,
                              hipStream_t stream)
{
    const float* x      = (const float*)d_in[0];
    const float* W_attn = (const float*)d_in[1];
    const float* b_attn = (const float*)d_in[2];
    const float* W_proj = (const float*)d_in[3];
    const float* b_proj = (const float*)d_in[4];
    float* out = (float*)d_out;

    char* ws = (char*)d_ws;
    size_t off = 0;
    auto alloc = [&](size_t bytes) -> void* {
        void* p = ws + off;
        off += (bytes + 255) & ~(size_t)255;
        return p;
    };
    unsigned short* xb   = (unsigned short*)alloc((size_t)BT_ * C_ * 2);
    unsigned short* Wab  = (unsigned short*)alloc((size_t)3 * C_ * C_ * 2);
    unsigned short* Wpb  = (unsigned short*)alloc((size_t)C_ * C_ * 2);
    unsigned short* qkvb = (unsigned short*)alloc((size_t)BT_ * 3 * C_ * 2);   // [B,T,3,H,D]
    unsigned short* yb   = (unsigned short*)alloc((size_t)BT_ * C_ * 2);
    const size_t vt_bytes = (size_t)BT_ * C_ * 2;
    const bool vdirect = (ws_size >= off + vt_bytes);
    unsigned short* vTb = vdirect ? (unsigned short*)alloc(vt_bytes)
                                  : xb;   // fallback: reuse xb after QKV GEMM

    prep_kernel<<<12288, 256, 0, stream>>>(x, xb, W_attn, Wab, W_proj, Wpb);

    if (vdirect) {
        qkv_gemm256_kernel<<<dim3(12, 32), 512, 0, stream>>>(
            xb, Wab, b_attn, qkvb, vTb);
    } else {
        gemm_bf16_kernel<0, 0><<<dim3(24, 64), 256, 0, stream>>>(
            xb, Wab, b_attn, nullptr, qkvb, nullptr, BT_, 3 * C_, C_);
        transpose_v_kernel<<<dim3(T_ / 64, B_ * H_), 256, 0, stream>>>(qkvb, vTb);
    }

    flash_attn_kernel<<<1024, 256, 0, stream>>>(qkvb, vTb, yb);

    gemm_bf16_kernel<1, 0><<<dim3(8, 64), 256, 0, stream>>>(
        yb, Wpb, b_proj, out, nullptr, nullptr, BT_, C_, C_);
}